// Round 4
// baseline (119.347 us; speedup 1.0000x reference)
//
#include <hip/hip_runtime.h>

typedef __bf16 bf16x8 __attribute__((ext_vector_type(8)));
typedef __bf16 bf16x4 __attribute__((ext_vector_type(4)));
typedef float  f32x4  __attribute__((ext_vector_type(4)));

#define GLD_LDS16(gsrc, ldst) \
  __builtin_amdgcn_global_load_lds((const __attribute__((address_space(1))) void*)(gsrc), \
                                   (__attribute__((address_space(3))) void*)(ldst), 16, 0, 0)

// ---------------- 1) GroupNorm partial sums ----------------
__global__ __launch_bounds__(256) void gn_partial_k(const float* __restrict__ x,
                                                    float* __restrict__ partial) {
  __shared__ float red[2][4];
  const int t = threadIdx.x;
  const float4* base = (const float4*)(x + (size_t)blockIdx.x * 4096);
  float s = 0.f, sq = 0.f;
#pragma unroll
  for (int kk = 0; kk < 4; ++kk) {
    float4 v = base[t + kk * 256];
    s  += (v.x + v.y) + (v.z + v.w);
    sq += (v.x * v.x + v.y * v.y) + (v.z * v.z + v.w * v.w);
  }
#pragma unroll
  for (int o = 32; o >= 1; o >>= 1) {
    s  += __shfl_down(s, o, 64);
    sq += __shfl_down(sq, o, 64);
  }
  if ((t & 63) == 0) { red[0][t >> 6] = s; red[1][t >> 6] = sq; }
  __syncthreads();
  if (t == 0) {
    float S  = (red[0][0] + red[0][1]) + (red[0][2] + red[0][3]);
    float SQ = (red[1][0] + red[1][1]) + (red[1][2] + red[1][3]);
    partial[blockIdx.x * 2]     = S;
    partial[blockIdx.x * 2 + 1] = SQ;
  }
}

// ---------------- 2) finalize mean/rstd ----------------
__global__ void gn_final_k(const float* __restrict__ partial, float* __restrict__ stats) {
  const int t = threadIdx.x;
  if (t < 32) {
    float S = 0.f, SQ = 0.f;
#pragma unroll
    for (int i = 0; i < 8; ++i) {
      S  += partial[(t * 8 + i) * 2];
      SQ += partial[(t * 8 + i) * 2 + 1];
    }
    float mean = S * (1.f / 32768.f);
    float var  = SQ * (1.f / 32768.f) - mean * mean;
    stats[t * 2]     = mean;
    stats[t * 2 + 1] = rsqrtf(fmaxf(var, 0.f) + 1e-5f);
  }
}

// ---------------- 3) fused GroupNorm-normalize + QKV 1x1 conv ----------------
// float4 LDS reads (stride 68 keeps 16B alignment; reads are same-address broadcasts).
__global__ __launch_bounds__(192) void qkv_k(const float* __restrict__ x,
                                             const float* __restrict__ stats,
                                             const float* __restrict__ gamma,
                                             const float* __restrict__ beta,
                                             const float* __restrict__ w_qkv,
                                             const float* __restrict__ b_qkv,
                                             __bf16* __restrict__ qo,
                                             __bf16* __restrict__ ko,
                                             __bf16* __restrict__ vto) {
  __shared__ float xn_lds[32 * 68];
  __shared__ float v_lds[64 * 33];
  const int t  = threadIdx.x;
  const int b  = blockIdx.x >> 7;
  const int s0 = (blockIdx.x & 127) * 32;

  for (int idx = t; idx < 2048; idx += 192) {
    int c = idx >> 5, px = idx & 31;
    float v  = x[((size_t)(b * 64 + c)) * 4096 + s0 + px];
    int   g2 = (b * 8 + (c >> 3)) * 2;
    xn_lds[px * 68 + c] = (v - stats[g2]) * stats[g2 + 1] * gamma[c] + beta[c];
  }
  float4 wr[16];
  const float4* wrow = (const float4*)(w_qkv + t * 64);
#pragma unroll
  for (int i = 0; i < 16; ++i) wr[i] = wrow[i];
  const float bias = b_qkv[t];
  __syncthreads();

  for (int px = 0; px < 32; ++px) {
    const float4* xr = (const float4*)&xn_lds[px * 68];
    float a0 = bias, a1 = 0.f, a2 = 0.f, a3 = 0.f;
#pragma unroll
    for (int i = 0; i < 16; i += 4) {
      float4 x0 = xr[i], x1 = xr[i + 1], x2 = xr[i + 2], x3 = xr[i + 3];
      a0 += wr[i    ].x * x0.x + wr[i    ].y * x0.y + wr[i    ].z * x0.z + wr[i    ].w * x0.w;
      a1 += wr[i + 1].x * x1.x + wr[i + 1].y * x1.y + wr[i + 1].z * x1.z + wr[i + 1].w * x1.w;
      a2 += wr[i + 2].x * x2.x + wr[i + 2].y * x2.y + wr[i + 2].z * x2.z + wr[i + 2].w * x2.w;
      a3 += wr[i + 3].x * x3.x + wr[i + 3].y * x3.y + wr[i + 3].z * x3.z + wr[i + 3].w * x3.w;
    }
    float acc = (a0 + a1) + (a2 + a3);
    if (t < 64)
      qo[((size_t)b * 4096 + s0 + px) * 64 + t] = (__bf16)(acc * 0.125f);
    else if (t < 128)
      ko[((size_t)b * 4096 + s0 + px) * 64 + (t - 64)] = (__bf16)acc;
    else
      v_lds[(t - 128) * 33 + px] = acc;
  }
  __syncthreads();
  for (int u = t; u < 2048; u += 192) {
    int rowc = u >> 5, px = u & 31;
    vto[((size_t)(b * 64 + rowc)) * 4096 + s0 + px] = (__bf16)v_lds[rowc * 33 + px];
  }
}

// ---------------- 4) flash attention: 64 q-rows/wave, 2-deep counted-vmcnt pipeline ----------------
// 512 blocks x 256 threads (4 waves) = exactly 2 blocks/CU (80KB LDS), zero dispatch tail.
// K/V tiles triple-buffered; stage(t+2) issued while computing tile t; s_waitcnt vmcnt(8)
// in steady state (tiles t+1,t+2 stay in flight across barriers — T3/T4). Raw s_barrier only.
__global__ __launch_bounds__(256, 2) void attn_k(const __bf16* __restrict__ q,
                                                 const __bf16* __restrict__ k,
                                                 const __bf16* __restrict__ vt,
                                                 __bf16* __restrict__ opart,
                                                 float* __restrict__ mlpart) {
  __shared__ __bf16 k_lds[3][4096];   // 64 keys x 64 d, swizzled slots (8KB each)
  __shared__ __bf16 v_lds[3][4096];   // 64 d x 64 keys, swizzled slots
  __shared__ __bf16 p_lds[4][4096];   // per-wave P^T 64 x 64, swizzled
  const int tid  = threadIdx.x;
  const int lane = tid & 63, w = tid >> 6;
  const int row  = lane & 15, grp = lane >> 4;

  // XCD-aware decode: batch pinned to an XCD pair.
  const int blk  = blockIdx.x;
  const int xcd  = blk & 7;
  const int b    = xcd >> 1;
  const int rest = blk >> 3;                       // 0..63
  const int seg  = rest >> 3;                      // 0..7
  const int qblk = (rest & 7) | ((xcd & 1) << 3);  // 0..15
  const int q0   = qblk * 256 + w * 64;            // this wave's 64 q-rows
  const int j0b  = seg * 512;

  const __bf16* qp = q  + (size_t)b * 4096 * 64;
  const __bf16* kp = k  + (size_t)b * 4096 * 64;
  const __bf16* vp = vt + (size_t)b * 64 * 4096;

  bf16x8 qf[4][2];
#pragma unroll
  for (int rt = 0; rt < 4; ++rt)
#pragma unroll
    for (int kc = 0; kc < 2; ++kc)
      qf[rt][kc] = *(const bf16x8*)(qp + (size_t)(q0 + rt * 16 + row) * 64 + kc * 32 + grp * 8);

  f32x4 acc[4][4];
#pragma unroll
  for (int rt = 0; rt < 4; ++rt)
#pragma unroll
    for (int dt = 0; dt < 4; ++dt) acc[rt][dt] = (f32x4){0.f, 0.f, 0.f, 0.f};
  float m[4] = {-1e30f, -1e30f, -1e30f, -1e30f}, l[4] = {0.f, 0.f, 0.f, 0.f};

  // staging offsets (constant per thread): 2 x 4KB rounds per 8KB tile
  const int soff0 = tid * 16, soff1 = tid * 16 + 4096;
  const int sj0 = soff0 >> 7, sj1 = soff1 >> 7;
  const int sc0 = ((soff0 >> 4) & 7) ^ (sj0 & 7);
  const int sc1 = ((soff1 >> 4) & 7) ^ (sj1 & 7);

  auto stage = [&](int buf, int j0) {
    GLD_LDS16(kp + (size_t)(j0 + sj0) * 64 + sc0 * 8, (char*)(&k_lds[buf][0]) + soff0);
    GLD_LDS16(kp + (size_t)(j0 + sj1) * 64 + sc1 * 8, (char*)(&k_lds[buf][0]) + soff1);
    GLD_LDS16(vp + (size_t)sj0 * 4096 + j0 + sc0 * 8, (char*)(&v_lds[buf][0]) + soff0);
    GLD_LDS16(vp + (size_t)sj1 * 4096 + j0 + sc1 * 8, (char*)(&v_lds[buf][0]) + soff1);
  };

  stage(0, j0b);
  stage(1, j0b + 64);

  char* const pbase = (char*)&p_lds[w][0];
  const int swz = (row & 7) << 3;

#pragma unroll
  for (int kt = 0; kt < 8; ++kt) {
    const int cur = kt % 3;
    if (kt < 6) stage((kt + 2) % 3, j0b + (kt + 2) * 64);   // 2-deep prefetch

    // tile kt's loads done; tiles kt+1, kt+2 stay in flight (counted vmcnt, T4)
    if (kt < 6)       asm volatile("s_waitcnt vmcnt(8)" ::: "memory");
    else if (kt == 6) asm volatile("s_waitcnt vmcnt(4)" ::: "memory");
    else              asm volatile("s_waitcnt vmcnt(0)" ::: "memory");
    __builtin_amdgcn_s_barrier();   // all waves' tile-kt loads landed

    const char* kbase = (const char*)&k_lds[cur][0];
    const char* vbase = (const char*)&v_lds[cur][0];

    // S^T = K · Q^T (scale folded into Q)
    f32x4 sa[4][4];
#pragma unroll
    for (int rt = 0; rt < 4; ++rt)
#pragma unroll
      for (int jt = 0; jt < 4; ++jt) sa[rt][jt] = (f32x4){0.f, 0.f, 0.f, 0.f};
    __builtin_amdgcn_s_setprio(1);
#pragma unroll
    for (int jt = 0; jt < 4; ++jt) {
      const int jr = jt * 16 + row;
      bf16x8 kf0 = *(const bf16x8*)(kbase + jr * 128 + ((grp ^ (row & 7)) << 4));
      bf16x8 kf1 = *(const bf16x8*)(kbase + jr * 128 + (((4 + grp) ^ (row & 7)) << 4));
#pragma unroll
      for (int rt = 0; rt < 4; ++rt) {
        sa[rt][jt] = __builtin_amdgcn_mfma_f32_16x16x32_bf16(kf0, qf[rt][0], sa[rt][jt], 0, 0, 0);
        sa[rt][jt] = __builtin_amdgcn_mfma_f32_16x16x32_bf16(kf1, qf[rt][1], sa[rt][jt], 0, 0, 0);
      }
    }
    __builtin_amdgcn_s_setprio(0);

    // online softmax (lane owns 16 keys of one q-row per rt)
#pragma unroll
    for (int rt = 0; rt < 4; ++rt) {
      float t0 = fmaxf(fmaxf(sa[rt][0][0], sa[rt][0][1]), fmaxf(sa[rt][0][2], sa[rt][0][3]));
      float t1 = fmaxf(fmaxf(sa[rt][1][0], sa[rt][1][1]), fmaxf(sa[rt][1][2], sa[rt][1][3]));
      float t2 = fmaxf(fmaxf(sa[rt][2][0], sa[rt][2][1]), fmaxf(sa[rt][2][2], sa[rt][2][3]));
      float t3 = fmaxf(fmaxf(sa[rt][3][0], sa[rt][3][1]), fmaxf(sa[rt][3][2], sa[rt][3][3]));
      float tmax = fmaxf(fmaxf(t0, t1), fmaxf(t2, t3));
      tmax = fmaxf(tmax, __shfl_xor(tmax, 16, 64));
      tmax = fmaxf(tmax, __shfl_xor(tmax, 32, 64));
      float mn = fmaxf(m[rt], tmax);
      float sf = __expf(m[rt] - mn);
      m[rt] = mn;
      float ls = 0.f;
#pragma unroll
      for (int jt = 0; jt < 4; ++jt) {
        float p0 = __expf(sa[rt][jt][0] - mn);
        float p1 = __expf(sa[rt][jt][1] - mn);
        float p2 = __expf(sa[rt][jt][2] - mn);
        float p3 = __expf(sa[rt][jt][3] - mn);
        ls += (p0 + p1) + (p2 + p3);
        bf16x4 pv = {(__bf16)p0, (__bf16)p1, (__bf16)p2, (__bf16)p3};
        *(bf16x4*)(pbase + ((rt * 16 + row) << 7) + ((((grp << 2) + (jt << 4)) ^ swz) << 1)) = pv;
      }
      l[rt] = l[rt] * sf + ls;
#pragma unroll
      for (int dt = 0; dt < 4; ++dt) {
        acc[rt][dt][0] *= sf; acc[rt][dt][1] *= sf;
        acc[rt][dt][2] *= sf; acc[rt][dt][3] *= sf;
      }
    }
    asm volatile("s_waitcnt lgkmcnt(0)" ::: "memory");  // own-wave P visibility

    // O^T += V^T · P^T
    __builtin_amdgcn_s_setprio(1);
#pragma unroll
    for (int kc = 0; kc < 2; ++kc) {
      const int koff = (((kc << 5) + (grp << 3)) ^ swz) << 1;
      bf16x8 af[4];
#pragma unroll
      for (int rt = 0; rt < 4; ++rt)
        af[rt] = *(const bf16x8*)(pbase + ((rt * 16 + row) << 7) + koff);
#pragma unroll
      for (int dt = 0; dt < 4; ++dt) {
        const int dr = dt * 16 + row;
        bf16x8 vf = *(const bf16x8*)(vbase + dr * 128 + ((((kc << 2) + grp) ^ (row & 7)) << 4));
#pragma unroll
        for (int rt = 0; rt < 4; ++rt)
          acc[rt][dt] = __builtin_amdgcn_mfma_f32_16x16x32_bf16(vf, af[rt], acc[rt][dt], 0, 0, 0);
      }
    }
    __builtin_amdgcn_s_setprio(0);

    if (kt < 7) __builtin_amdgcn_s_barrier();  // safe to overwrite buf (kt)%3 next iter
  }

  // epilogue: un-normalized O^T (bf16) + (m, l) for split-K combine
#pragma unroll
  for (int rt = 0; rt < 4; ++rt) {
    float lt = l[rt];
    lt += __shfl_xor(lt, 16, 64);
    lt += __shfl_xor(lt, 32, 64);
    const int qrow = q0 + rt * 16 + row;
    __bf16* ob = opart + ((size_t)(b * 8 + seg) * 4096 + qrow) * 64;
#pragma unroll
    for (int dt = 0; dt < 4; ++dt) {
      bf16x4 ov = {(__bf16)acc[rt][dt][0], (__bf16)acc[rt][dt][1],
                   (__bf16)acc[rt][dt][2], (__bf16)acc[rt][dt][3]};
      *(bf16x4*)(ob + dt * 16 + grp * 4) = ov;
    }
    if (grp == 0) {
      float2 mlv; mlv.x = m[rt]; mlv.y = lt;
      *(float2*)(mlpart + ((size_t)(b * 8 + seg) * 4096 + qrow) * 2) = mlv;
    }
  }
}

// ---------------- 5) split-K combine + proj 1x1 conv + residual ----------------
__global__ __launch_bounds__(256) void proj_k(const __bf16* __restrict__ opart,
                                              const float* __restrict__ mlpart,
                                              const float* __restrict__ x,
                                              const float* __restrict__ w_proj,
                                              const float* __restrict__ b_proj,
                                              float* __restrict__ out) {
  __shared__ float wseg[8][32];
  __shared__ float a_lds[32 * 68];
  __shared__ float o_lds[64 * 33];
  const int t  = threadIdx.x;
  const int b  = blockIdx.x >> 7;
  const int s0 = (blockIdx.x & 127) * 32;

  if (t < 32) {
    const int rowg = s0 + t;
    float ms[8], ls[8], es[8];
    float M = -1e30f;
#pragma unroll
    for (int s = 0; s < 8; ++s) {
      float2 ml = *(const float2*)(mlpart + ((size_t)(b * 8 + s) * 4096 + rowg) * 2);
      ms[s] = ml.x; ls[s] = ml.y;
      M = fmaxf(M, ms[s]);
    }
    float L = 0.f;
#pragma unroll
    for (int s = 0; s < 8; ++s) { es[s] = __expf(ms[s] - M); L += es[s] * ls[s]; }
    float invL = 1.f / L;
#pragma unroll
    for (int s = 0; s < 8; ++s) wseg[s][t] = es[s] * invL;
  }
  __syncthreads();

  for (int i = t; i < 512; i += 256) {
    const int px = i >> 4, c4 = i & 15;
    const __bf16* obase = opart + ((size_t)(b * 8) * 4096 + s0 + px) * 64 + c4 * 4;
    float4 a = {0.f, 0.f, 0.f, 0.f};
#pragma unroll
    for (int s = 0; s < 8; ++s) {
      bf16x4 v = *(const bf16x4*)(obase + (size_t)s * 4096 * 64);
      float wv = wseg[s][px];
      a.x += wv * (float)v[0]; a.y += wv * (float)v[1];
      a.z += wv * (float)v[2]; a.w += wv * (float)v[3];
    }
    *(float4*)(&a_lds[px * 68 + c4 * 4]) = a;
  }

  const int o = t & 63, wg = t >> 6;
  float4 wr[16];
  const float4* wrow = (const float4*)(w_proj + o * 64);
#pragma unroll
  for (int i = 0; i < 16; ++i) wr[i] = wrow[i];
  const float bias = b_proj[o];
  __syncthreads();

  for (int pp = 0; pp < 8; ++pp) {
    const int px = wg * 8 + pp;
    const float4* ar = (const float4*)&a_lds[px * 68];
    float a0 = bias, a1 = 0.f, a2 = 0.f, a3 = 0.f;
#pragma unroll
    for (int i = 0; i < 16; i += 4) {
      float4 x0 = ar[i], x1 = ar[i + 1], x2 = ar[i + 2], x3 = ar[i + 3];
      a0 += wr[i    ].x * x0.x + wr[i    ].y * x0.y + wr[i    ].z * x0.z + wr[i    ].w * x0.w;
      a1 += wr[i + 1].x * x1.x + wr[i + 1].y * x1.y + wr[i + 1].z * x1.z + wr[i + 1].w * x1.w;
      a2 += wr[i + 2].x * x2.x + wr[i + 2].y * x2.y + wr[i + 2].z * x2.z + wr[i + 2].w * x2.w;
      a3 += wr[i + 3].x * x3.x + wr[i + 3].y * x3.y + wr[i + 3].z * x3.z + wr[i + 3].w * x3.w;
    }
    o_lds[o * 33 + px] = (a0 + a1) + (a2 + a3);
  }
  __syncthreads();
  for (int idx = t; idx < 2048; idx += 256) {
    const int c = idx >> 5, px = idx & 31;
    const size_t gi = ((size_t)(b * 64 + c)) * 4096 + s0 + px;
    out[gi] = o_lds[c * 33 + px] + x[gi];
  }
}

// ---------------- launch ----------------
extern "C" void kernel_launch(void* const* d_in, const int* in_sizes, int n_in,
                              void* d_out, int out_size, void* d_ws, size_t ws_size,
                              hipStream_t stream) {
  const float* x      = (const float*)d_in[0];
  const float* gamma  = (const float*)d_in[1];
  const float* beta   = (const float*)d_in[2];
  const float* w_qkv  = (const float*)d_in[3];
  const float* b_qkv  = (const float*)d_in[4];
  const float* w_proj = (const float*)d_in[5];
  const float* b_proj = (const float*)d_in[6];
  float* out = (float*)d_out;

  char* ws = (char*)d_ws;
  float*  partial = (float*)ws;                          // 512 f32
  float*  stats   = partial + 512;                       // 64 f32
  __bf16* qb  = (__bf16*)(ws + 4096);                    // 2MB
  __bf16* kb  = qb  + (size_t)4 * 4096 * 64;             // 2MB
  __bf16* vtb = kb  + (size_t)4 * 4096 * 64;             // 2MB
  __bf16* opart = vtb + (size_t)4 * 4096 * 64;           // 16MB (bf16)
  float*  mlpart = (float*)(opart + (size_t)4 * 8 * 4096 * 64);  // 1MB

  gn_partial_k<<<256, 256, 0, stream>>>(x, partial);
  gn_final_k<<<1, 64, 0, stream>>>(partial, stats);
  qkv_k<<<512, 192, 0, stream>>>(x, stats, gamma, beta, w_qkv, b_qkv, qb, kb, vtb);
  attn_k<<<512, 256, 0, stream>>>(qb, kb, vtb, opart, mlpart);
  proj_k<<<512, 256, 0, stream>>>(opart, mlpart, x, w_proj, b_proj, out);
}

// Round 5
// 78.432 us; speedup vs baseline: 1.5217x; 1.5217x over previous
//
#include <hip/hip_runtime.h>

typedef __bf16 bf16x8 __attribute__((ext_vector_type(8)));
typedef __bf16 bf16x4 __attribute__((ext_vector_type(4)));
typedef float  f32x4  __attribute__((ext_vector_type(4)));

#define GLD_LDS16(gsrc, ldst) \
  __builtin_amdgcn_global_load_lds((const __attribute__((address_space(1))) void*)(gsrc), \
                                   (__attribute__((address_space(3))) void*)(ldst), 16, 0, 0)

// ---------------- 1) GroupNorm partial sums ----------------
__global__ __launch_bounds__(256) void gn_partial_k(const float* __restrict__ x,
                                                    float* __restrict__ partial) {
  __shared__ float red[2][4];
  const int t = threadIdx.x;
  const float4* base = (const float4*)(x + (size_t)blockIdx.x * 4096);
  float s = 0.f, sq = 0.f;
#pragma unroll
  for (int kk = 0; kk < 4; ++kk) {
    float4 v = base[t + kk * 256];
    s  += (v.x + v.y) + (v.z + v.w);
    sq += (v.x * v.x + v.y * v.y) + (v.z * v.z + v.w * v.w);
  }
#pragma unroll
  for (int o = 32; o >= 1; o >>= 1) {
    s  += __shfl_down(s, o, 64);
    sq += __shfl_down(sq, o, 64);
  }
  if ((t & 63) == 0) { red[0][t >> 6] = s; red[1][t >> 6] = sq; }
  __syncthreads();
  if (t == 0) {
    float S  = (red[0][0] + red[0][1]) + (red[0][2] + red[0][3]);
    float SQ = (red[1][0] + red[1][1]) + (red[1][2] + red[1][3]);
    partial[blockIdx.x * 2]     = S;
    partial[blockIdx.x * 2 + 1] = SQ;
  }
}

// ---------------- 2) finalize mean/rstd ----------------
__global__ void gn_final_k(const float* __restrict__ partial, float* __restrict__ stats) {
  const int t = threadIdx.x;
  if (t < 32) {
    float S = 0.f, SQ = 0.f;
#pragma unroll
    for (int i = 0; i < 8; ++i) {
      S  += partial[(t * 8 + i) * 2];
      SQ += partial[(t * 8 + i) * 2 + 1];
    }
    float mean = S * (1.f / 32768.f);
    float var  = SQ * (1.f / 32768.f) - mean * mean;
    stats[t * 2]     = mean;
    stats[t * 2 + 1] = rsqrtf(fmaxf(var, 0.f) + 1e-5f);
  }
}

// ---------------- 3) fused GroupNorm-normalize + QKV 1x1 conv ----------------
// float4 LDS reads (stride 68 keeps 16B alignment; reads are same-address broadcasts).
__global__ __launch_bounds__(192) void qkv_k(const float* __restrict__ x,
                                             const float* __restrict__ stats,
                                             const float* __restrict__ gamma,
                                             const float* __restrict__ beta,
                                             const float* __restrict__ w_qkv,
                                             const float* __restrict__ b_qkv,
                                             __bf16* __restrict__ qo,
                                             __bf16* __restrict__ ko,
                                             __bf16* __restrict__ vto) {
  __shared__ float xn_lds[32 * 68];
  __shared__ float v_lds[64 * 33];
  const int t  = threadIdx.x;
  const int b  = blockIdx.x >> 7;
  const int s0 = (blockIdx.x & 127) * 32;

  for (int idx = t; idx < 2048; idx += 192) {
    int c = idx >> 5, px = idx & 31;
    float v  = x[((size_t)(b * 64 + c)) * 4096 + s0 + px];
    int   g2 = (b * 8 + (c >> 3)) * 2;
    xn_lds[px * 68 + c] = (v - stats[g2]) * stats[g2 + 1] * gamma[c] + beta[c];
  }
  float4 wr[16];
  const float4* wrow = (const float4*)(w_qkv + t * 64);
#pragma unroll
  for (int i = 0; i < 16; ++i) wr[i] = wrow[i];
  const float bias = b_qkv[t];
  __syncthreads();

  for (int px = 0; px < 32; ++px) {
    const float4* xr = (const float4*)&xn_lds[px * 68];
    float a0 = bias, a1 = 0.f, a2 = 0.f, a3 = 0.f;
#pragma unroll
    for (int i = 0; i < 16; i += 4) {
      float4 x0 = xr[i], x1 = xr[i + 1], x2 = xr[i + 2], x3 = xr[i + 3];
      a0 += wr[i    ].x * x0.x + wr[i    ].y * x0.y + wr[i    ].z * x0.z + wr[i    ].w * x0.w;
      a1 += wr[i + 1].x * x1.x + wr[i + 1].y * x1.y + wr[i + 1].z * x1.z + wr[i + 1].w * x1.w;
      a2 += wr[i + 2].x * x2.x + wr[i + 2].y * x2.y + wr[i + 2].z * x2.z + wr[i + 2].w * x2.w;
      a3 += wr[i + 3].x * x3.x + wr[i + 3].y * x3.y + wr[i + 3].z * x3.z + wr[i + 3].w * x3.w;
    }
    float acc = (a0 + a1) + (a2 + a3);
    if (t < 64)
      qo[((size_t)b * 4096 + s0 + px) * 64 + t] = (__bf16)(acc * 0.125f);
    else if (t < 128)
      ko[((size_t)b * 4096 + s0 + px) * 64 + (t - 64)] = (__bf16)acc;
    else
      v_lds[(t - 128) * 33 + px] = acc;
  }
  __syncthreads();
  for (int u = t; u < 2048; u += 192) {
    int rowc = u >> 5, px = u & 31;
    vto[((size_t)(b * 64 + rowc)) * 4096 + s0 + px] = (__bf16)v_lds[rowc * 33 + px];
  }
}

// ---------------- 4) flash attention: 32 q-rows/wave, 2-deep counted-vmcnt pipeline ----------------
// 1024 blocks x 256 threads (4 waves). Block = (batch, seg of 512 keys, 128 q-rows).
// K/V triple-buffered in LDS; stage(t+2) issued at top of compute(t); steady-state
// s_waitcnt vmcnt(8) keeps tiles t+1,t+2 in flight across barriers (T3/T4).
// Register budget: sa 32 + acc 32 + qf 16 + temps (~120) -> no spill (round-4 lesson).
__global__ __launch_bounds__(256, 2) void attn_k(const __bf16* __restrict__ q,
                                                 const __bf16* __restrict__ k,
                                                 const __bf16* __restrict__ vt,
                                                 __bf16* __restrict__ opart,
                                                 float* __restrict__ mlpart) {
  __shared__ __bf16 k_lds[3][4096];   // 64 keys x 64 d, swizzled slots (8KB each)
  __shared__ __bf16 v_lds[3][4096];   // 64 d x 64 keys, swizzled slots
  __shared__ __bf16 p_lds[4][2048];   // per-wave P^T 32 x 64, swizzled (4KB each)
  const int tid  = threadIdx.x;
  const int lane = tid & 63, w = tid >> 6;
  const int row  = lane & 15, grp = lane >> 4;

  // XCD-aware decode: batch pinned to an XCD pair; consecutive same-XCD blocks share seg.
  const int blk  = blockIdx.x;
  const int xcd  = blk & 7;
  const int b    = xcd >> 1;
  const int rest = blk >> 3;                        // 0..127
  const int seg  = rest >> 4;                       // 0..7
  const int qblk = (rest & 15) | ((xcd & 1) << 4);  // 0..31
  const int q0   = qblk * 128 + w * 32;             // this wave's 32 q-rows
  const int j0b  = seg * 512;

  const __bf16* qp = q  + (size_t)b * 4096 * 64;
  const __bf16* kp = k  + (size_t)b * 4096 * 64;
  const __bf16* vp = vt + (size_t)b * 64 * 4096;

  bf16x8 qf[2][2];
#pragma unroll
  for (int rt = 0; rt < 2; ++rt)
#pragma unroll
    for (int kc = 0; kc < 2; ++kc)
      qf[rt][kc] = *(const bf16x8*)(qp + (size_t)(q0 + rt * 16 + row) * 64 + kc * 32 + grp * 8);

  f32x4 acc[2][4];
#pragma unroll
  for (int rt = 0; rt < 2; ++rt)
#pragma unroll
    for (int dt = 0; dt < 4; ++dt) acc[rt][dt] = (f32x4){0.f, 0.f, 0.f, 0.f};
  float m[2] = {-1e30f, -1e30f}, l[2] = {0.f, 0.f};

  // staging offsets (constant per thread): 2 x 4KB rounds per 8KB tile
  const int soff0 = tid * 16, soff1 = tid * 16 + 4096;
  const int sj0 = soff0 >> 7, sj1 = soff1 >> 7;
  const int sc0 = ((soff0 >> 4) & 7) ^ (sj0 & 7);
  const int sc1 = ((soff1 >> 4) & 7) ^ (sj1 & 7);

  auto stage = [&](int buf, int j0) {
    GLD_LDS16(kp + (size_t)(j0 + sj0) * 64 + sc0 * 8, (char*)(&k_lds[buf][0]) + soff0);
    GLD_LDS16(kp + (size_t)(j0 + sj1) * 64 + sc1 * 8, (char*)(&k_lds[buf][0]) + soff1);
    GLD_LDS16(vp + (size_t)sj0 * 4096 + j0 + sc0 * 8, (char*)(&v_lds[buf][0]) + soff0);
    GLD_LDS16(vp + (size_t)sj1 * 4096 + j0 + sc1 * 8, (char*)(&v_lds[buf][0]) + soff1);
  };

  stage(0, j0b);
  stage(1, j0b + 64);

  char* const pbase = (char*)&p_lds[w][0];
  const int swz = (row & 7) << 3;

#pragma unroll
  for (int kt = 0; kt < 8; ++kt) {
    const int cur = kt % 3;
    if (kt < 6) stage((kt + 2) % 3, j0b + (kt + 2) * 64);   // 2-deep prefetch

    // wait for tile kt only; tiles kt+1, kt+2 stay in flight (counted vmcnt, T4).
    // Ledger: qf(8 loads) are oldest and drain first at kt=0.
    if (kt < 6)       asm volatile("s_waitcnt vmcnt(8)" ::: "memory");
    else if (kt == 6) asm volatile("s_waitcnt vmcnt(4)" ::: "memory");
    else              asm volatile("s_waitcnt vmcnt(0)" ::: "memory");
    __builtin_amdgcn_s_barrier();   // all waves' tile-kt loads landed

    const char* kbase = (const char*)&k_lds[cur][0];
    const char* vbase = (const char*)&v_lds[cur][0];

    // S^T = K · Q^T (scale folded into Q)
    f32x4 sa[2][4];
#pragma unroll
    for (int rt = 0; rt < 2; ++rt)
#pragma unroll
      for (int jt = 0; jt < 4; ++jt) sa[rt][jt] = (f32x4){0.f, 0.f, 0.f, 0.f};
    __builtin_amdgcn_s_setprio(1);
#pragma unroll
    for (int jt = 0; jt < 4; ++jt) {
      const int jr = jt * 16 + row;
      bf16x8 kf0 = *(const bf16x8*)(kbase + jr * 128 + ((grp ^ (row & 7)) << 4));
      bf16x8 kf1 = *(const bf16x8*)(kbase + jr * 128 + (((4 + grp) ^ (row & 7)) << 4));
      sa[0][jt] = __builtin_amdgcn_mfma_f32_16x16x32_bf16(kf0, qf[0][0], sa[0][jt], 0, 0, 0);
      sa[1][jt] = __builtin_amdgcn_mfma_f32_16x16x32_bf16(kf0, qf[1][0], sa[1][jt], 0, 0, 0);
      sa[0][jt] = __builtin_amdgcn_mfma_f32_16x16x32_bf16(kf1, qf[0][1], sa[0][jt], 0, 0, 0);
      sa[1][jt] = __builtin_amdgcn_mfma_f32_16x16x32_bf16(kf1, qf[1][1], sa[1][jt], 0, 0, 0);
    }
    __builtin_amdgcn_s_setprio(0);

    // online softmax (lane owns 16 keys of one q-row per rt)
#pragma unroll
    for (int rt = 0; rt < 2; ++rt) {
      float t0 = fmaxf(fmaxf(sa[rt][0][0], sa[rt][0][1]), fmaxf(sa[rt][0][2], sa[rt][0][3]));
      float t1 = fmaxf(fmaxf(sa[rt][1][0], sa[rt][1][1]), fmaxf(sa[rt][1][2], sa[rt][1][3]));
      float t2 = fmaxf(fmaxf(sa[rt][2][0], sa[rt][2][1]), fmaxf(sa[rt][2][2], sa[rt][2][3]));
      float t3 = fmaxf(fmaxf(sa[rt][3][0], sa[rt][3][1]), fmaxf(sa[rt][3][2], sa[rt][3][3]));
      float tmax = fmaxf(fmaxf(t0, t1), fmaxf(t2, t3));
      tmax = fmaxf(tmax, __shfl_xor(tmax, 16, 64));
      tmax = fmaxf(tmax, __shfl_xor(tmax, 32, 64));
      float mn = fmaxf(m[rt], tmax);
      float sf = __expf(m[rt] - mn);
      m[rt] = mn;
      float ls = 0.f;
#pragma unroll
      for (int jt = 0; jt < 4; ++jt) {
        float p0 = __expf(sa[rt][jt][0] - mn);
        float p1 = __expf(sa[rt][jt][1] - mn);
        float p2 = __expf(sa[rt][jt][2] - mn);
        float p3 = __expf(sa[rt][jt][3] - mn);
        ls += (p0 + p1) + (p2 + p3);
        bf16x4 pv = {(__bf16)p0, (__bf16)p1, (__bf16)p2, (__bf16)p3};
        *(bf16x4*)(pbase + ((rt * 16 + row) << 7) + ((((grp << 2) + (jt << 4)) ^ swz) << 1)) = pv;
      }
      l[rt] = l[rt] * sf + ls;
#pragma unroll
      for (int dt = 0; dt < 4; ++dt) {
        acc[rt][dt][0] *= sf; acc[rt][dt][1] *= sf;
        acc[rt][dt][2] *= sf; acc[rt][dt][3] *= sf;
      }
    }
    asm volatile("s_waitcnt lgkmcnt(0)" ::: "memory");  // own-wave P visibility

    // O^T += V^T · P^T
    __builtin_amdgcn_s_setprio(1);
#pragma unroll
    for (int kc = 0; kc < 2; ++kc) {
      const int koff = (((kc << 5) + (grp << 3)) ^ swz) << 1;
      bf16x8 af0 = *(const bf16x8*)(pbase + (row << 7) + koff);
      bf16x8 af1 = *(const bf16x8*)(pbase + ((16 + row) << 7) + koff);
#pragma unroll
      for (int dt = 0; dt < 4; ++dt) {
        const int dr = dt * 16 + row;
        bf16x8 vf = *(const bf16x8*)(vbase + dr * 128 + ((((kc << 2) + grp) ^ (row & 7)) << 4));
        acc[0][dt] = __builtin_amdgcn_mfma_f32_16x16x32_bf16(vf, af0, acc[0][dt], 0, 0, 0);
        acc[1][dt] = __builtin_amdgcn_mfma_f32_16x16x32_bf16(vf, af1, acc[1][dt], 0, 0, 0);
      }
    }
    __builtin_amdgcn_s_setprio(0);

    if (kt < 7) __builtin_amdgcn_s_barrier();  // all waves done with tile kt -> its buffer reusable
  }

  // epilogue: un-normalized O^T (bf16) + (m, l) for split-K combine
#pragma unroll
  for (int rt = 0; rt < 2; ++rt) {
    float lt = l[rt];
    lt += __shfl_xor(lt, 16, 64);
    lt += __shfl_xor(lt, 32, 64);
    const int qrow = q0 + rt * 16 + row;
    __bf16* ob = opart + ((size_t)(b * 8 + seg) * 4096 + qrow) * 64;
#pragma unroll
    for (int dt = 0; dt < 4; ++dt) {
      bf16x4 ov = {(__bf16)acc[rt][dt][0], (__bf16)acc[rt][dt][1],
                   (__bf16)acc[rt][dt][2], (__bf16)acc[rt][dt][3]};
      *(bf16x4*)(ob + dt * 16 + grp * 4) = ov;
    }
    if (grp == 0) {
      float2 mlv; mlv.x = m[rt]; mlv.y = lt;
      *(float2*)(mlpart + ((size_t)(b * 8 + seg) * 4096 + qrow) * 2) = mlv;
    }
  }
}

// ---------------- 5) split-K combine + proj 1x1 conv + residual ----------------
__global__ __launch_bounds__(256) void proj_k(const __bf16* __restrict__ opart,
                                              const float* __restrict__ mlpart,
                                              const float* __restrict__ x,
                                              const float* __restrict__ w_proj,
                                              const float* __restrict__ b_proj,
                                              float* __restrict__ out) {
  __shared__ float wseg[8][32];
  __shared__ float a_lds[32 * 68];
  __shared__ float o_lds[64 * 33];
  const int t  = threadIdx.x;
  const int b  = blockIdx.x >> 7;
  const int s0 = (blockIdx.x & 127) * 32;

  if (t < 32) {
    const int rowg = s0 + t;
    float ms[8], ls[8], es[8];
    float M = -1e30f;
#pragma unroll
    for (int s = 0; s < 8; ++s) {
      float2 ml = *(const float2*)(mlpart + ((size_t)(b * 8 + s) * 4096 + rowg) * 2);
      ms[s] = ml.x; ls[s] = ml.y;
      M = fmaxf(M, ms[s]);
    }
    float L = 0.f;
#pragma unroll
    for (int s = 0; s < 8; ++s) { es[s] = __expf(ms[s] - M); L += es[s] * ls[s]; }
    float invL = 1.f / L;
#pragma unroll
    for (int s = 0; s < 8; ++s) wseg[s][t] = es[s] * invL;
  }
  __syncthreads();

  for (int i = t; i < 512; i += 256) {
    const int px = i >> 4, c4 = i & 15;
    const __bf16* obase = opart + ((size_t)(b * 8) * 4096 + s0 + px) * 64 + c4 * 4;
    float4 a = {0.f, 0.f, 0.f, 0.f};
#pragma unroll
    for (int s = 0; s < 8; ++s) {
      bf16x4 v = *(const bf16x4*)(obase + (size_t)s * 4096 * 64);
      float wv = wseg[s][px];
      a.x += wv * (float)v[0]; a.y += wv * (float)v[1];
      a.z += wv * (float)v[2]; a.w += wv * (float)v[3];
    }
    *(float4*)(&a_lds[px * 68 + c4 * 4]) = a;
  }

  const int o = t & 63, wg = t >> 6;
  float4 wr[16];
  const float4* wrow = (const float4*)(w_proj + o * 64);
#pragma unroll
  for (int i = 0; i < 16; ++i) wr[i] = wrow[i];
  const float bias = b_proj[o];
  __syncthreads();

  for (int pp = 0; pp < 8; ++pp) {
    const int px = wg * 8 + pp;
    const float4* ar = (const float4*)&a_lds[px * 68];
    float a0 = bias, a1 = 0.f, a2 = 0.f, a3 = 0.f;
#pragma unroll
    for (int i = 0; i < 16; i += 4) {
      float4 x0 = ar[i], x1 = ar[i + 1], x2 = ar[i + 2], x3 = ar[i + 3];
      a0 += wr[i    ].x * x0.x + wr[i    ].y * x0.y + wr[i    ].z * x0.z + wr[i    ].w * x0.w;
      a1 += wr[i + 1].x * x1.x + wr[i + 1].y * x1.y + wr[i + 1].z * x1.z + wr[i + 1].w * x1.w;
      a2 += wr[i + 2].x * x2.x + wr[i + 2].y * x2.y + wr[i + 2].z * x2.z + wr[i + 2].w * x2.w;
      a3 += wr[i + 3].x * x3.x + wr[i + 3].y * x3.y + wr[i + 3].z * x3.z + wr[i + 3].w * x3.w;
    }
    o_lds[o * 33 + px] = (a0 + a1) + (a2 + a3);
  }
  __syncthreads();
  for (int idx = t; idx < 2048; idx += 256) {
    const int c = idx >> 5, px = idx & 31;
    const size_t gi = ((size_t)(b * 64 + c)) * 4096 + s0 + px;
    out[gi] = o_lds[c * 33 + px] + x[gi];
  }
}

// ---------------- launch ----------------
extern "C" void kernel_launch(void* const* d_in, const int* in_sizes, int n_in,
                              void* d_out, int out_size, void* d_ws, size_t ws_size,
                              hipStream_t stream) {
  const float* x      = (const float*)d_in[0];
  const float* gamma  = (const float*)d_in[1];
  const float* beta   = (const float*)d_in[2];
  const float* w_qkv  = (const float*)d_in[3];
  const float* b_qkv  = (const float*)d_in[4];
  const float* w_proj = (const float*)d_in[5];
  const float* b_proj = (const float*)d_in[6];
  float* out = (float*)d_out;

  char* ws = (char*)d_ws;
  float*  partial = (float*)ws;                          // 512 f32
  float*  stats   = partial + 512;                       // 64 f32
  __bf16* qb  = (__bf16*)(ws + 4096);                    // 2MB
  __bf16* kb  = qb  + (size_t)4 * 4096 * 64;             // 2MB
  __bf16* vtb = kb  + (size_t)4 * 4096 * 64;             // 2MB
  __bf16* opart = vtb + (size_t)4 * 4096 * 64;           // 16MB (bf16)
  float*  mlpart = (float*)(opart + (size_t)4 * 8 * 4096 * 64);  // 1MB

  gn_partial_k<<<256, 256, 0, stream>>>(x, partial);
  gn_final_k<<<1, 64, 0, stream>>>(partial, stats);
  qkv_k<<<512, 192, 0, stream>>>(x, stats, gamma, beta, w_qkv, b_qkv, qb, kb, vtb);
  attn_k<<<1024, 256, 0, stream>>>(qb, kb, vtb, opart, mlpart);
  proj_k<<<512, 256, 0, stream>>>(opart, mlpart, x, w_proj, b_proj, out);
}